// Round 1
// baseline (683.315 us; speedup 1.0000x reference)
//
#include <hip/hip_runtime.h>

typedef unsigned long long u64;

#define B_N 8192
#define L_N 1024
#define M_N 128
#define C_N 8          // chunks over L
#define CH_N 128       // steps per chunk (L/C)
#define HALF_N 512

// ws layout (bytes)
#define OFF_W    0            // w[i][m]  f32: 1024*128*4 = 512KB
#define OFF_R    0x80000      // r[i][m]  f32: 512KB
#define OFF_BITS 0x100000     // bits[b][word] u64: 8192*16*8 = 1MB
#define OFF_PP   0x200000     // pp[16][128] f32: 8KB
#define OFF_RQ   0x210000     // Rq[c][m][b] bf16: 8*128*8192*2 = 16MB

// ---------------- K0: pack spins to bits (inputs are 0/1) ----------------
__global__ __launch_bounds__(256) void k_pack(const int* __restrict__ inp, u64* __restrict__ bits) {
    int g = blockIdx.x * 256 + threadIdx.x;     // g in [0, B*L)
    int v = inp[g];
    u64 m = __ballot(v != 0);
    if ((threadIdx.x & 63) == 0) bits[g >> 6] = m;
}

// ---------------- K1a: partial products of eps0 over 64-step blocks ------
__global__ void k_eps_pp(const float* __restrict__ eps, float* __restrict__ pp) {
    int m = threadIdx.x, j = blockIdx.x;        // 16 blocks x 128 threads
    const float* e0 = eps + m * L_N;            // eps[0][m][i]
    float p = 1.f;
    for (int i = 64 * j; i < 64 * j + 64; ++i) p *= e0[i];
    pp[j * M_N + m] = p;
}

// ---------------- K1b: w[i][m] = E0_i*(e0-e1), r[i][m] = e1/e0 -----------
__global__ void k_eps_wr(const float* __restrict__ eps, const float* __restrict__ pp,
                         float* __restrict__ w, float* __restrict__ r) {
    int m = threadIdx.x, j = blockIdx.x;
    float E = 1.f;
    for (int jj = 0; jj < j; ++jj) E *= pp[jj * M_N + m];
    const float* e0 = eps + m * L_N;
    const float* e1 = eps + (M_N + m) * L_N;
    for (int i = 64 * j; i < 64 * j + 64; ++i) {
        float a = e0[i], b = e1[i];
        w[i * M_N + m] = E * (a - b);   // E0 exclusive of i
        r[i * M_N + m] = b / a;
        E *= a;
    }
}

// ---------------- K2: per-chunk masked ratio products --------------------
__global__ __launch_bounds__(256) void k_chunkprod(const u64* __restrict__ bits,
        const float* __restrict__ r, unsigned short* __restrict__ Rq) {
    int c = blockIdx.x >> 5;                       // 32 blocks per chunk (uniform!)
    int b = (blockIdx.x & 31) * 256 + threadIdx.x; // consecutive b within wave
    u64 wrd[2];
    wrd[0] = bits[b * 16 + 2 * c];
    wrd[1] = bits[b * 16 + 2 * c + 1];
    float R[M_N];
    #pragma unroll
    for (int m = 0; m < M_N; ++m) R[m] = 1.f;
    for (int h = 0; h < 2; ++h) {
        u64 wv = wrd[h];
        for (int tt = 0; tt < 64; ++tt) {
            int tg = c * CH_N + h * 64 + tt;
            const float* rr = r + tg * M_N;
            bool s = (wv >> tt) & 1;
            if (s) {
                #pragma unroll
                for (int m = 0; m < M_N; ++m) R[m] *= rr[m];
            }
        }
    }
    #pragma unroll
    for (int m = 0; m < M_N; ++m) {
        union { float f; unsigned u; } x; x.f = R[m];
        unsigned u = x.u + 0x7FFFu + ((x.u >> 16) & 1u);   // RNE to bf16
        Rq[(c * M_N + m) * B_N + b] = (unsigned short)(u >> 16);
    }
}

// ---------------- K3: main loop — dot + contribution + update ------------
__global__ __launch_bounds__(256) void k_main(const u64* __restrict__ bits,
        const float* __restrict__ w, const float* __restrict__ r,
        const unsigned short* __restrict__ Rq, float* __restrict__ out) {
    int c = blockIdx.x >> 5;                        // uniform
    int b = (blockIdx.x & 31) * 256 + threadIdx.x;

    float R[M_N];
    #pragma unroll
    for (int m = 0; m < M_N; ++m) R[m] = 1.f;
    for (int cp = 0; cp < c; ++cp) {
        #pragma unroll
        for (int m = 0; m < M_N; ++m) {
            union { unsigned u; float f; } x;
            x.u = ((unsigned)Rq[(cp * M_N + m) * B_N + b]) << 16;
            R[m] *= x.f;
        }
    }
    int n1 = 0;
    for (int k = 0; k < 2 * c; ++k) n1 += __popcll(bits[b * 16 + k]);
    int n0 = c * CH_N - n1;
    u64 wrd[2];
    wrd[0] = bits[b * 16 + 2 * c];
    wrd[1] = bits[b * 16 + 2 * c + 1];

    float sum = 0.f;
    for (int h = 0; h < 2; ++h) {
        u64 wv = wrd[h];
        for (int tt = 0; tt < 64; ++tt) {
            int tg = c * CH_N + h * 64 + tt;
            const float* wr = w + tg * M_N;
            const float* rr = r + tg * M_N;
            float d0 = 0.f, d1 = 0.f, d2 = 0.f, d3 = 0.f;
            #pragma unroll
            for (int m = 0; m < M_N; m += 4) {
                d0 += R[m + 0] * wr[m + 0];
                d1 += R[m + 1] * wr[m + 1];
                d2 += R[m + 2] * wr[m + 2];
                d3 += R[m + 3] * wr[m + 3];
            }
            float Dv = (d0 + d1) + (d2 + d3);
            bool s = (wv >> tt) & 1;
            bool valid = (n0 < HALF_N) && (n1 < HALF_N);
            float ad = fabsf(Dv);
            float contr = -fmaxf(s ? Dv : -Dv, 0.f)
                          - 0.5f * __logf(1.f + __expf(-2.f * ad));
            sum += valid ? contr : 0.f;
            if (s) {
                n1++;
                #pragma unroll
                for (int m = 0; m < M_N; ++m) R[m] *= rr[m];
            } else {
                n0++;
            }
        }
    }
    atomicAdd(&out[b], sum);
}

extern "C" void kernel_launch(void* const* d_in, const int* in_sizes, int n_in,
                              void* d_out, int out_size, void* d_ws, size_t ws_size,
                              hipStream_t stream) {
    const int*   inputs  = (const int*)d_in[0];     // (B, L) int32
    const float* epsilon = (const float*)d_in[1];   // (D, M, L) f32
    float* out = (float*)d_out;                     // (B,) f32

    char* ws = (char*)d_ws;
    float* w_tab  = (float*)(ws + OFF_W);
    float* r_tab  = (float*)(ws + OFF_R);
    u64*   bits   = (u64*)  (ws + OFF_BITS);
    float* pp     = (float*)(ws + OFF_PP);
    unsigned short* Rq = (unsigned short*)(ws + OFF_RQ);

    k_pack<<<(B_N * L_N) / 256, 256, 0, stream>>>(inputs, bits);
    k_eps_pp<<<L_N / 64, M_N, 0, stream>>>(epsilon, pp);
    k_eps_wr<<<L_N / 64, M_N, 0, stream>>>(epsilon, pp, w_tab, r_tab);
    hipMemsetAsync(d_out, 0, B_N * sizeof(float), stream);
    k_chunkprod<<<(B_N * C_N) / 256, 256, 0, stream>>>(bits, r_tab, Rq);
    k_main<<<(B_N * C_N) / 256, 256, 0, stream>>>(bits, w_tab, r_tab, Rq, out);
}

// Round 2
// 378.795 us; speedup vs baseline: 1.8039x; 1.8039x over previous
//
#include <hip/hip_runtime.h>

typedef unsigned long long u64;

#define B_N 8192
#define L_N 1024
#define M_N 128
#define C_N 16         // chunks over L
#define CH_N 64        // steps per chunk (L/C)
#define HALF_N 512
#define MP2 64         // M/2 (float2 count)
#define MP4 32         // M/4 (float4 count)

// ws layout (bytes)
#define OFF_W    0            // w[i][m]  f32: 1024*128*4 = 512KB
#define OFF_R    0x80000      // r[i][m]  f32: 512KB
#define OFF_BITS 0x100000     // bits[b][16] u64: 8192*16*8 = 1MB
#define OFF_PP   0x200000     // pp[16][128] f32: 8KB
#define OFF_RQ   0x210000     // Rq[c][m][b] bf16: 16*128*8192*2 = 32MB

__device__ __forceinline__ unsigned short f32_bf16(float f) {
    union { float f; unsigned u; } x; x.f = f;
    unsigned u = x.u + 0x7FFFu + ((x.u >> 16) & 1u);   // RNE
    return (unsigned short)(u >> 16);
}
__device__ __forceinline__ float bf16_f32(unsigned short h) {
    union { unsigned u; float f; } x; x.u = ((unsigned)h) << 16;
    return x.f;
}

// ---------------- K0: pack spins to bits (inputs are 0/1) ----------------
__global__ __launch_bounds__(256) void k_pack(const int* __restrict__ inp, u64* __restrict__ bits) {
    int g = blockIdx.x * 256 + threadIdx.x;     // g in [0, B*L)
    int v = inp[g];
    u64 m = __ballot(v != 0);
    if ((threadIdx.x & 63) == 0) bits[g >> 6] = m;   // word = b*16 + i/64 = b*16 + c
}

// ---------------- K1a: partial products of eps0 over 64-step blocks ------
__global__ void k_eps_pp(const float* __restrict__ eps, float* __restrict__ pp) {
    int m = threadIdx.x, j = blockIdx.x;        // 16 blocks x 128 threads
    const float* e0 = eps + m * L_N;            // eps[0][m][i]
    float p = 1.f;
    for (int i = 64 * j; i < 64 * j + 64; ++i) p *= e0[i];
    pp[j * M_N + m] = p;
}

// ---------------- K1b: w[i][m] = E0_i*(e0-e1), r[i][m] = e1/e0 -----------
__global__ void k_eps_wr(const float* __restrict__ eps, const float* __restrict__ pp,
                         float* __restrict__ w, float* __restrict__ r) {
    int m = threadIdx.x, j = blockIdx.x;
    float E = 1.f;
    for (int jj = 0; jj < j; ++jj) E *= pp[jj * M_N + m];
    const float* e0 = eps + m * L_N;
    const float* e1 = eps + (M_N + m) * L_N;
    for (int i = 64 * j; i < 64 * j + 64; ++i) {
        float a = e0[i], b = e1[i];
        w[i * M_N + m] = E * (a - b);   // E0 exclusive of i
        r[i * M_N + m] = b / a;
        E *= a;
    }
}

// ---------------- K2: per-chunk masked ratio products --------------------
__global__ __launch_bounds__(256) void k_chunkprod(const u64* __restrict__ bits,
        const float* __restrict__ r, unsigned short* __restrict__ Rq) {
    __shared__ float4 rbuf[CH_N * MP4];                // 32KB
    int c = blockIdx.x >> 5;                           // uniform per block
    int b = (blockIdx.x & 31) * 256 + threadIdx.x;     // consecutive b within wave

    const float4* rg = (const float4*)(r + (size_t)c * CH_N * M_N);
    for (int k = threadIdx.x; k < CH_N * MP4; k += 256) rbuf[k] = rg[k];
    __syncthreads();

    u64 wv = bits[b * 16 + c];
    float2 R[MP2];
    #pragma unroll
    for (int k = 0; k < MP2; ++k) R[k] = make_float2(1.f, 1.f);

    for (int tt = 0; tt < CH_N; ++tt) {
        if ((wv >> tt) & 1) {
            const float4* rr = &rbuf[tt * MP4];
            #pragma unroll
            for (int j = 0; j < MP4; ++j) {
                float4 v = rr[j];
                R[2 * j].x     *= v.x; R[2 * j].y     *= v.y;
                R[2 * j + 1].x *= v.z; R[2 * j + 1].y *= v.w;
            }
        }
    }
    #pragma unroll
    for (int k = 0; k < MP2; ++k) {
        Rq[((size_t)(c * M_N + 2 * k)) * B_N + b]     = f32_bf16(R[k].x);
        Rq[((size_t)(c * M_N + 2 * k + 1)) * B_N + b] = f32_bf16(R[k].y);
    }
}

// ---------------- K2b: in-place exclusive cumulative prefix over chunks --
__global__ __launch_bounds__(256) void k_prefix(unsigned short* __restrict__ Rq) {
    int t = blockIdx.x * 256 + threadIdx.x;    // t in [0, M*B)
    int m = t >> 13;                           // /B_N
    int b = t & (B_N - 1);
    float p = 1.f;
    for (int c = 0; c < C_N; ++c) {
        size_t idx = ((size_t)(c * M_N + m)) * B_N + b;
        float f = bf16_f32(Rq[idx]);
        Rq[idx] = f32_bf16(p);                 // exclusive prefix overwrites chunk prod
        p *= f;
    }
}

// ---------------- K3: main loop — dot + contribution + update ------------
__global__ __launch_bounds__(256) void k_main(const u64* __restrict__ bits,
        const float* __restrict__ w, const float* __restrict__ r,
        const unsigned short* __restrict__ Rq, float* __restrict__ out) {
    __shared__ float4 wbuf[CH_N * MP4];                // 32KB
    __shared__ float4 rbuf[CH_N * MP4];                // 32KB
    int c = blockIdx.x >> 5;                           // uniform per block
    int b = (blockIdx.x & 31) * 256 + threadIdx.x;

    // load prefix row (bf16, coalesced across lanes in b)
    float2 R[MP2];
    #pragma unroll
    for (int k = 0; k < MP2; ++k) {
        unsigned short u0 = Rq[((size_t)(c * M_N + 2 * k)) * B_N + b];
        unsigned short u1 = Rq[((size_t)(c * M_N + 2 * k + 1)) * B_N + b];
        R[k] = make_float2(bf16_f32(u0), bf16_f32(u1));
    }

    // stage chunk tables into LDS
    const float4* wg = (const float4*)(w + (size_t)c * CH_N * M_N);
    const float4* rg = (const float4*)(r + (size_t)c * CH_N * M_N);
    for (int k = threadIdx.x; k < CH_N * MP4; k += 256) { wbuf[k] = wg[k]; rbuf[k] = rg[k]; }
    __syncthreads();

    // spin counts before this chunk
    int n1 = 0;
    for (int k = 0; k < c; ++k) n1 += __popcll(bits[b * 16 + k]);
    int n0 = c * CH_N - n1;
    u64 wv = bits[b * 16 + c];

    float sum = 0.f;
    for (int tt = 0; tt < CH_N; ++tt) {
        const float4* wr = &wbuf[tt * MP4];
        float2 a0 = make_float2(0.f, 0.f), a1 = a0, a2 = a0, a3 = a0;
        #pragma unroll
        for (int j = 0; j < MP4; j += 4) {
            float4 v0 = wr[j], v1 = wr[j + 1], v2 = wr[j + 2], v3 = wr[j + 3];
            a0.x += R[2 * j].x * v0.x;     a0.y += R[2 * j].y * v0.y;
            a1.x += R[2 * j + 1].x * v0.z; a1.y += R[2 * j + 1].y * v0.w;
            a2.x += R[2 * j + 2].x * v1.x; a2.y += R[2 * j + 2].y * v1.y;
            a3.x += R[2 * j + 3].x * v1.z; a3.y += R[2 * j + 3].y * v1.w;
            a0.x += R[2 * j + 4].x * v2.x; a0.y += R[2 * j + 4].y * v2.y;
            a1.x += R[2 * j + 5].x * v2.z; a1.y += R[2 * j + 5].y * v2.w;
            a2.x += R[2 * j + 6].x * v3.x; a2.y += R[2 * j + 6].y * v3.y;
            a3.x += R[2 * j + 7].x * v3.z; a3.y += R[2 * j + 7].y * v3.w;
        }
        float Dv = ((a0.x + a0.y) + (a1.x + a1.y)) + ((a2.x + a2.y) + (a3.x + a3.y));

        bool s = (wv >> tt) & 1;
        bool valid = (n0 < HALF_N) && (n1 < HALF_N);
        float ad = fabsf(Dv);
        float contr = -fmaxf(s ? Dv : -Dv, 0.f)
                      - 0.5f * __logf(1.f + __expf(-2.f * ad));
        sum += valid ? contr : 0.f;

        if (s) {
            n1++;
            const float4* rr = &rbuf[tt * MP4];
            #pragma unroll
            for (int j = 0; j < MP4; ++j) {
                float4 v = rr[j];
                R[2 * j].x     *= v.x; R[2 * j].y     *= v.y;
                R[2 * j + 1].x *= v.z; R[2 * j + 1].y *= v.w;
            }
        } else {
            n0++;
        }
    }
    atomicAdd(&out[b], sum);
}

extern "C" void kernel_launch(void* const* d_in, const int* in_sizes, int n_in,
                              void* d_out, int out_size, void* d_ws, size_t ws_size,
                              hipStream_t stream) {
    const int*   inputs  = (const int*)d_in[0];     // (B, L) int32
    const float* epsilon = (const float*)d_in[1];   // (D, M, L) f32
    float* out = (float*)d_out;                     // (B,) f32

    char* ws = (char*)d_ws;
    float* w_tab  = (float*)(ws + OFF_W);
    float* r_tab  = (float*)(ws + OFF_R);
    u64*   bits   = (u64*)  (ws + OFF_BITS);
    float* pp     = (float*)(ws + OFF_PP);
    unsigned short* Rq = (unsigned short*)(ws + OFF_RQ);

    k_pack<<<(B_N * L_N) / 256, 256, 0, stream>>>(inputs, bits);
    k_eps_pp<<<L_N / 64, M_N, 0, stream>>>(epsilon, pp);
    k_eps_wr<<<L_N / 64, M_N, 0, stream>>>(epsilon, pp, w_tab, r_tab);
    hipMemsetAsync(d_out, 0, B_N * sizeof(float), stream);
    k_chunkprod<<<(B_N * C_N) / 256, 256, 0, stream>>>(bits, r_tab, Rq);
    k_prefix<<<(M_N * B_N) / 256, 256, 0, stream>>>(Rq);
    k_main<<<(B_N * C_N) / 256, 256, 0, stream>>>(bits, w_tab, r_tab, Rq, out);
}

// Round 3
// 281.835 us; speedup vs baseline: 2.4245x; 1.3440x over previous
//
#include <hip/hip_runtime.h>

typedef unsigned long long u64;
typedef unsigned int uint32;

#define B_N 8192
#define L_N 1024
#define M_N 128
#define C_N 16         // chunks over L
#define CH_N 64        // steps per chunk (L/C)
#define HALF_N 512

// ws layout (bytes)
#define OFF_W    0            // w[i][phys_m]  f32 (quarter-rotated): 512KB
#define OFF_R    0x80000      // r[i][phys_m]  f32 (quarter-rotated): 512KB
#define OFF_BITS 0x100000     // bits[b][16] u64: 1MB
#define OFF_PP   0x200000     // pp[16][128] f32: 8KB
#define OFF_RQ   0x210000     // Rq[c][b][m] bf16: 16*8192*128*2 = 32MB

__device__ __forceinline__ unsigned short f32_bf16(float f) {
    union { float f; unsigned u; } x; x.f = f;
    unsigned u = x.u + 0x7FFFu + ((x.u >> 16) & 1u);   // RNE
    return (unsigned short)(u >> 16);
}
__device__ __forceinline__ float bf16lo(uint32 w) {
    union { unsigned u; float f; } x; x.u = w << 16; return x.f;
}
__device__ __forceinline__ float bf16hi(uint32 w) {
    union { unsigned u; float f; } x; x.u = w & 0xFFFF0000u; return x.f;
}

// ---------------- K0: pack spins to bits (inputs are 0/1) ----------------
__global__ __launch_bounds__(256) void k_pack(const int* __restrict__ inp, u64* __restrict__ bits) {
    int g = blockIdx.x * 256 + threadIdx.x;     // g in [0, B*L)
    int v = inp[g];
    u64 m = __ballot(v != 0);
    if ((threadIdx.x & 63) == 0) bits[g >> 6] = m;   // word = b*16 + c
}

// ---------------- K1a: partial products of eps0 over 64-step blocks ------
__global__ void k_eps_pp(const float* __restrict__ eps, float* __restrict__ pp) {
    int m = threadIdx.x, j = blockIdx.x;        // 16 blocks x 128 threads
    const float* e0 = eps + m * L_N;
    float p = 1.f;
    for (int i = 64 * j; i < 64 * j + 64; ++i) p *= e0[i];
    pp[j * M_N + m] = p;
}

// ------- K1b: rotated tables: w[i][phys]=E0*(e0-e1), r[i][phys]=e1/e0 ----
// phys = q*32 + ((k + q*8) & 31)  for logical m = q*32+k  (bank-conflict rot)
__global__ void k_eps_wr(const float* __restrict__ eps, const float* __restrict__ pp,
                         float* __restrict__ w, float* __restrict__ r) {
    int m = threadIdx.x, j = blockIdx.x;
    int q = m >> 5, k = m & 31;
    int phys = q * 32 + ((k + q * 8) & 31);
    float E = 1.f;
    for (int jj = 0; jj < j; ++jj) E *= pp[jj * M_N + m];
    const float* e0 = eps + m * L_N;
    const float* e1 = eps + (M_N + m) * L_N;
    for (int i = 64 * j; i < 64 * j + 64; ++i) {
        float a = e0[i], b = e1[i];
        w[i * M_N + phys] = E * (a - b);   // E0 exclusive of i
        r[i * M_N + phys] = b / a;
        E *= a;
    }
}

// ---------------- K2: per-chunk masked ratio products (S=4, NB=4) --------
__global__ __launch_bounds__(256, 2) void k_chunkprod(const u64* __restrict__ bits,
        const float* __restrict__ r, unsigned short* __restrict__ Rq) {
    __shared__ float rbuf[CH_N * M_N];                 // 32KB
    int c = blockIdx.x & (C_N - 1);
    int bblk = blockIdx.x >> 4;
    int lane = threadIdx.x & 63, wid = threadIdx.x >> 6;
    int q = lane & 3, g = lane >> 2;
    int b0 = bblk * 256 + wid * 64 + g * 4;

    {
        const float4* src = (const float4*)(r + (size_t)c * CH_N * M_N);
        float4* dst = (float4*)rbuf;
        for (int t = threadIdx.x; t < CH_N * M_N / 4; t += 256) dst[t] = src[t];
    }
    __syncthreads();

    u64 wb[4];
    #pragma unroll
    for (int nb = 0; nb < 4; ++nb) wb[nb] = bits[(size_t)(b0 + nb) * 16 + c];

    float R[4][32];
    #pragma unroll
    for (int nb = 0; nb < 4; ++nb)
        #pragma unroll
        for (int k = 0; k < 32; ++k) R[nb][k] = 1.f;

    for (int tt = 0; tt < CH_N; ++tt) {
        int base = tt * M_N + q * 32;
        float4 rv[8];
        #pragma unroll
        for (int jj = 0; jj < 8; ++jj)
            rv[jj] = *(const float4*)&rbuf[base + ((q * 8 + 4 * jj) & 31)];
        #pragma unroll
        for (int nb = 0; nb < 4; ++nb) {
            if ((wb[nb] >> tt) & 1) {
                #pragma unroll
                for (int jj = 0; jj < 8; ++jj) {
                    R[nb][4 * jj + 0] *= rv[jj].x;
                    R[nb][4 * jj + 1] *= rv[jj].y;
                    R[nb][4 * jj + 2] *= rv[jj].z;
                    R[nb][4 * jj + 3] *= rv[jj].w;
                }
            }
        }
    }
    #pragma unroll
    for (int nb = 0; nb < 4; ++nb) {
        uint32 pk[16];
        #pragma unroll
        for (int kk = 0; kk < 16; ++kk) {
            uint32 lo = f32_bf16(R[nb][2 * kk]);
            uint32 hi = f32_bf16(R[nb][2 * kk + 1]);
            pk[kk] = lo | (hi << 16);
        }
        uint4* dst = (uint4*)(Rq + ((size_t)c * B_N + (b0 + nb)) * M_N + q * 32);
        dst[0] = make_uint4(pk[0], pk[1], pk[2], pk[3]);
        dst[1] = make_uint4(pk[4], pk[5], pk[6], pk[7]);
        dst[2] = make_uint4(pk[8], pk[9], pk[10], pk[11]);
        dst[3] = make_uint4(pk[12], pk[13], pk[14], pk[15]);
    }
}

// ---------------- K2b: in-place exclusive prefix over chunks -------------
__global__ __launch_bounds__(256) void k_prefix(unsigned short* __restrict__ Rq) {
    int t = blockIdx.x * 256 + threadIdx.x;    // t in [0, B*M)
    int b = t >> 7, m = t & 127;
    float p = 1.f;
    for (int c = 0; c < C_N; ++c) {
        size_t idx = ((size_t)c * B_N + b) * M_N + m;
        union { unsigned u; float f; } x; x.u = ((unsigned)Rq[idx]) << 16;
        Rq[idx] = f32_bf16(p);
        p *= x.f;
    }
}

// ---------------- K3: main loop (S=4 quarters, NB=4 b per group) ---------
__global__ __launch_bounds__(256, 2) void k_main(const u64* __restrict__ bits,
        const float* __restrict__ w, const float* __restrict__ r,
        const unsigned short* __restrict__ Rq, float* __restrict__ out) {
    __shared__ float wbuf[CH_N * M_N];                 // 32KB
    __shared__ float rbuf[CH_N * M_N];                 // 32KB
    int c = blockIdx.x & (C_N - 1);
    int bblk = blockIdx.x >> 4;
    int lane = threadIdx.x & 63, wid = threadIdx.x >> 6;
    int q = lane & 3, g = lane >> 2;
    int b0 = bblk * 256 + wid * 64 + g * 4;
    int b_own = b0 + q;

    {
        const float4* srcw = (const float4*)(w + (size_t)c * CH_N * M_N);
        const float4* srcr = (const float4*)(r + (size_t)c * CH_N * M_N);
        float4* dw = (float4*)wbuf; float4* dr = (float4*)rbuf;
        for (int t = threadIdx.x; t < CH_N * M_N / 4; t += 256) { dw[t] = srcw[t]; dr[t] = srcr[t]; }
    }

    // prefix load (bf16, [c][b][m] layout — 16B contiguous per b)
    float R[4][32];
    #pragma unroll
    for (int nb = 0; nb < 4; ++nb) {
        const uint4* src = (const uint4*)(Rq + ((size_t)c * B_N + (b0 + nb)) * M_N + q * 32);
        #pragma unroll
        for (int u_ = 0; u_ < 4; ++u_) {
            uint4 pv = src[u_];
            R[nb][u_ * 8 + 0] = bf16lo(pv.x); R[nb][u_ * 8 + 1] = bf16hi(pv.x);
            R[nb][u_ * 8 + 2] = bf16lo(pv.y); R[nb][u_ * 8 + 3] = bf16hi(pv.y);
            R[nb][u_ * 8 + 4] = bf16lo(pv.z); R[nb][u_ * 8 + 5] = bf16hi(pv.z);
            R[nb][u_ * 8 + 6] = bf16lo(pv.w); R[nb][u_ * 8 + 7] = bf16hi(pv.w);
        }
    }

    u64 wb[4];
    #pragma unroll
    for (int nb = 0; nb < 4; ++nb) wb[nb] = bits[(size_t)(b0 + nb) * 16 + c];
    u64 ownbits = wb[0];
    if (q == 1) ownbits = wb[1];
    if (q == 2) ownbits = wb[2];
    if (q == 3) ownbits = wb[3];

    int n1 = 0;
    for (int k = 0; k < c; ++k) n1 += __popcll(bits[(size_t)b_own * 16 + k]);
    int n0 = c * CH_N - n1;

    __syncthreads();

    float sum = 0.f;
    for (int tt = 0; tt < CH_N; ++tt) {
        int base = tt * M_N + q * 32;
        float d0[4] = {0.f, 0.f, 0.f, 0.f}, d1[4] = {0.f, 0.f, 0.f, 0.f};
        #pragma unroll
        for (int jj = 0; jj < 8; jj += 2) {
            float4 va = *(const float4*)&wbuf[base + ((q * 8 + 4 * jj) & 31)];
            float4 vb = *(const float4*)&wbuf[base + ((q * 8 + 4 * jj + 4) & 31)];
            #pragma unroll
            for (int nb = 0; nb < 4; ++nb) {
                d0[nb] += R[nb][4 * jj + 0] * va.x + R[nb][4 * jj + 1] * va.y
                        + R[nb][4 * jj + 2] * va.z + R[nb][4 * jj + 3] * va.w;
                d1[nb] += R[nb][4 * jj + 4] * vb.x + R[nb][4 * jj + 5] * vb.y
                        + R[nb][4 * jj + 6] * vb.z + R[nb][4 * jj + 7] * vb.w;
            }
        }
        float d[4];
        #pragma unroll
        for (int nb = 0; nb < 4; ++nb) {
            float v = d0[nb] + d1[nb];
            v += __shfl_xor(v, 1);
            v += __shfl_xor(v, 2);
            d[nb] = v;
        }
        float Dv = d[0];
        if (q == 1) Dv = d[1];
        if (q == 2) Dv = d[2];
        if (q == 3) Dv = d[3];

        bool s = (ownbits >> tt) & 1;
        bool valid = (n0 < HALF_N) && (n1 < HALF_N);
        float ad = fabsf(Dv);
        float contr = -fmaxf(s ? Dv : -Dv, 0.f)
                      - 0.5f * __logf(1.f + __expf(-2.f * ad));
        sum += valid ? contr : 0.f;
        if (s) n1++; else n0++;

        float4 rv[8];
        #pragma unroll
        for (int jj = 0; jj < 8; ++jj)
            rv[jj] = *(const float4*)&rbuf[base + ((q * 8 + 4 * jj) & 31)];
        #pragma unroll
        for (int nb = 0; nb < 4; ++nb) {
            if ((wb[nb] >> tt) & 1) {
                #pragma unroll
                for (int jj = 0; jj < 8; ++jj) {
                    R[nb][4 * jj + 0] *= rv[jj].x;
                    R[nb][4 * jj + 1] *= rv[jj].y;
                    R[nb][4 * jj + 2] *= rv[jj].z;
                    R[nb][4 * jj + 3] *= rv[jj].w;
                }
            }
        }
    }
    atomicAdd(&out[b_own], sum);
}

extern "C" void kernel_launch(void* const* d_in, const int* in_sizes, int n_in,
                              void* d_out, int out_size, void* d_ws, size_t ws_size,
                              hipStream_t stream) {
    const int*   inputs  = (const int*)d_in[0];     // (B, L) int32
    const float* epsilon = (const float*)d_in[1];   // (D, M, L) f32
    float* out = (float*)d_out;                     // (B,) f32

    char* ws = (char*)d_ws;
    float* w_tab  = (float*)(ws + OFF_W);
    float* r_tab  = (float*)(ws + OFF_R);
    u64*   bits   = (u64*)  (ws + OFF_BITS);
    float* pp     = (float*)(ws + OFF_PP);
    unsigned short* Rq = (unsigned short*)(ws + OFF_RQ);

    k_pack<<<(B_N * L_N) / 256, 256, 0, stream>>>(inputs, bits);
    k_eps_pp<<<L_N / 64, M_N, 0, stream>>>(epsilon, pp);
    k_eps_wr<<<L_N / 64, M_N, 0, stream>>>(epsilon, pp, w_tab, r_tab);
    hipMemsetAsync(d_out, 0, B_N * sizeof(float), stream);
    k_chunkprod<<<(B_N / 256) * C_N, 256, 0, stream>>>(bits, r_tab, Rq);
    k_prefix<<<(B_N * M_N) / 256, 256, 0, stream>>>(Rq);
    k_main<<<(B_N / 256) * C_N, 256, 0, stream>>>(bits, w_tab, r_tab, Rq, out);
}

// Round 4
// 215.026 us; speedup vs baseline: 3.1778x; 1.3107x over previous
//
#include <hip/hip_runtime.h>

typedef unsigned long long u64;
typedef unsigned int uint32;
typedef short short8 __attribute__((ext_vector_type(8)));
typedef float f32x4 __attribute__((ext_vector_type(4)));

#define B_N 8192
#define L_N 1024
#define M_N 128
#define C_N 16         // chunks over L
#define CH_N 64        // steps per chunk
#define HALF_N 512
#define SL 20          // padded 16-float slice stride (banks: s*20%32 all-distinct groups)
#define ROWF (8 * SL)  // 160 floats per staged step row

// ws layout (bytes)
#define OFF_W    0            // w[i][m]  f32: 512KB
#define OFF_R    0x80000      // r[i][m]  f32: 512KB
#define OFF_BITS 0x100000     // bits[b][16] u64: 1MB
#define OFF_PP   0x200000     // pp[16][128] f32: 8KB
#define OFF_LR   0x208000     // lrT[m][t] bf16: 128*1024*2 = 256KB
#define OFF_RQ   0x248000     // Rq[c][b][m] bf16: 16*8192*128*2 = 32MB

__device__ __forceinline__ unsigned short f32_bf16(float f) {
    union { float f; unsigned u; } x; x.f = f;
    unsigned u = x.u + 0x7FFFu + ((x.u >> 16) & 1u);   // RNE
    return (unsigned short)(u >> 16);
}
__device__ __forceinline__ float bf16lo(uint32 w) {
    union { unsigned u; float f; } x; x.u = w << 16; return x.f;
}
__device__ __forceinline__ float bf16hi(uint32 w) {
    union { unsigned u; float f; } x; x.u = w & 0xFFFF0000u; return x.f;
}

// ---------------- K0: pack spins to bits (inputs are 0/1) ----------------
__global__ __launch_bounds__(256) void k_pack(const int* __restrict__ inp, u64* __restrict__ bits) {
    int g = blockIdx.x * 256 + threadIdx.x;
    int v = inp[g];
    u64 m = __ballot(v != 0);
    if ((threadIdx.x & 63) == 0) bits[g >> 6] = m;   // word = b*16 + c
}

// ---------------- K1a: partial products of eps0 over 64-step blocks ------
__global__ void k_eps_pp(const float* __restrict__ eps, float* __restrict__ pp) {
    int m = threadIdx.x, j = blockIdx.x;
    const float* e0 = eps + m * L_N;
    float p = 1.f;
    for (int i = 64 * j; i < 64 * j + 64; ++i) p *= e0[i];
    pp[j * M_N + m] = p;
}

// ------- K1b: w[i][m]=E0*(e0-e1), r[i][m]=e1/e0, lrT[m][i]=bf16(log2 r) --
__global__ void k_eps_wr(const float* __restrict__ eps, const float* __restrict__ pp,
                         float* __restrict__ w, float* __restrict__ r,
                         unsigned short* __restrict__ lrT) {
    int m = threadIdx.x, j = blockIdx.x;
    float E = 1.f;
    for (int jj = 0; jj < j; ++jj) E *= pp[jj * M_N + m];
    const float* e0 = eps + m * L_N;
    const float* e1 = eps + (M_N + m) * L_N;
    for (int i = 64 * j; i < 64 * j + 64; ++i) {
        float a = e0[i], b = e1[i];
        float rat = b / a;
        w[i * M_N + m] = E * (a - b);   // E0 exclusive of i
        r[i * M_N + m] = rat;
        lrT[(size_t)m * L_N + i] = f32_bf16(__log2f(rat));
        E *= a;
    }
}

// ---- K2: MFMA chunk log-sums + in-register cumsum + exp2 -> Rq ----------
// D[b][m] = sum_t S[b][t] * lr[t][m]; A-frag A[row=lane&15][k=quad*8+j],
// B-frag B[k=quad*8+j][col=lane&15], C/D: col=lane&15, row=quad*4+reg.
__global__ __launch_bounds__(256) void k_slog(const u64* __restrict__ bits,
        const unsigned short* __restrict__ lrT, unsigned short* __restrict__ Rq) {
    int wid = threadIdx.x >> 6, lane = threadIdx.x & 63;
    int btile = blockIdx.x * 2 + (wid >> 1);
    int mbase = (wid & 1) * 64;
    int col = lane & 15, quad = lane >> 4;
    int b_row = btile * 16 + col;            // A-fragment row owner

    f32x4 cum[4];
    #pragma unroll
    for (int mt = 0; mt < 4; ++mt) cum[mt] = (f32x4){0.f, 0.f, 0.f, 0.f};

    for (int c = 0; c < C_N; ++c) {
        // write exclusive prefix: Rq[c] = exp2(cum)
        #pragma unroll
        for (int mt = 0; mt < 4; ++mt) {
            #pragma unroll
            for (int reg = 0; reg < 4; ++reg) {
                int b = btile * 16 + quad * 4 + reg;
                int m = mbase + mt * 16 + col;
                Rq[((size_t)c * B_N + b) * M_N + m] = f32_bf16(exp2f(cum[mt][reg]));
            }
        }
        // A fragments from bit word of own row
        u64 wv = bits[(size_t)b_row * 16 + c];
        short8 a0, a1;
        #pragma unroll
        for (int j = 0; j < 8; ++j) {
            a0[j] = (short)((((wv >> (quad * 8 + j)) & 1) != 0) ? 0x3F80 : 0);
            a1[j] = (short)((((wv >> (32 + quad * 8 + j)) & 1) != 0) ? 0x3F80 : 0);
        }
        #pragma unroll
        for (int mt = 0; mt < 4; ++mt) {
            int m = mbase + mt * 16 + col;
            const unsigned short* bp = lrT + (size_t)m * L_N + c * 64 + quad * 8;
            union { uint4 u; short8 s; } bf0, bf1;
            bf0.u = *(const uint4*)bp;
            bf1.u = *(const uint4*)(bp + 32);
            f32x4 acc = (f32x4){0.f, 0.f, 0.f, 0.f};
            acc = __builtin_amdgcn_mfma_f32_16x16x32_bf16(a0, bf0.s, acc, 0, 0, 0);
            acc = __builtin_amdgcn_mfma_f32_16x16x32_bf16(a1, bf1.s, acc, 0, 0, 0);
            cum[mt] += acc;
        }
    }
}

// ---------------- K3: main loop (8-lane groups, NB=4, half-chunk LDS) ----
__global__ __launch_bounds__(256, 4) void k_main(const u64* __restrict__ bits,
        const float* __restrict__ w, const float* __restrict__ r,
        const unsigned short* __restrict__ Rq, float* __restrict__ out) {
    __shared__ float wbuf[32 * ROWF];   // 20KB
    __shared__ float rbuf[32 * ROWF];   // 20KB
    int c = blockIdx.x & (C_N - 1);
    int bblk = blockIdx.x >> 4;
    int lane = threadIdx.x & 63, wid = threadIdx.x >> 6;
    int s = lane & 7, g = lane >> 3;
    int b0 = bblk * 128 + wid * 32 + g * 4;
    int b_own = b0 + (s & 3);

    // prefix load: R[nb][k], m = s*16 + k (logical layout)
    float R[4][16];
    #pragma unroll
    for (int nb = 0; nb < 4; ++nb) {
        const uint4* src = (const uint4*)(Rq + ((size_t)c * B_N + (b0 + nb)) * M_N + s * 16);
        #pragma unroll
        for (int u_ = 0; u_ < 2; ++u_) {
            uint4 pv = src[u_];
            R[nb][u_ * 8 + 0] = bf16lo(pv.x); R[nb][u_ * 8 + 1] = bf16hi(pv.x);
            R[nb][u_ * 8 + 2] = bf16lo(pv.y); R[nb][u_ * 8 + 3] = bf16hi(pv.y);
            R[nb][u_ * 8 + 4] = bf16lo(pv.z); R[nb][u_ * 8 + 5] = bf16hi(pv.z);
            R[nb][u_ * 8 + 6] = bf16lo(pv.w); R[nb][u_ * 8 + 7] = bf16hi(pv.w);
        }
    }
    int n1 = 0;
    for (int k = 0; k < c; ++k) n1 += __popcll(bits[(size_t)b_own * 16 + k]);
    int n0 = c * CH_N - n1;

    float sum = 0.f;
    for (int h = 0; h < 2; ++h) {
        __syncthreads();
        const float4* srcw = (const float4*)(w + ((size_t)c * CH_N + h * 32) * M_N);
        const float4* srcr = (const float4*)(r + ((size_t)c * CH_N + h * 32) * M_N);
        for (int t = threadIdx.x; t < 32 * 32; t += 256) {
            int i = t >> 5, mq = t & 31;
            int dst = i * ROWF + (mq >> 2) * SL + (mq & 3) * 4;
            *(float4*)&wbuf[dst] = srcw[t];
            *(float4*)&rbuf[dst] = srcr[t];
        }
        __syncthreads();

        uint32 wh[4];
        #pragma unroll
        for (int nb = 0; nb < 4; ++nb)
            wh[nb] = (uint32)(bits[(size_t)(b0 + nb) * 16 + c] >> (h * 32));
        uint32 owa = (s & 1) ? wh[1] : wh[0];
        uint32 owb = (s & 1) ? wh[3] : wh[2];
        uint32 ow = (s & 2) ? owb : owa;

        for (int tt = 0; tt < 32; ++tt) {
            int base = tt * ROWF + s * SL;
            float4 va = *(const float4*)&wbuf[base];
            float4 vb = *(const float4*)&wbuf[base + 4];
            float4 vc = *(const float4*)&wbuf[base + 8];
            float4 vd = *(const float4*)&wbuf[base + 12];
            float d[4];
            #pragma unroll
            for (int nb = 0; nb < 4; ++nb) {
                d[nb] = R[nb][0] * va.x + R[nb][1] * va.y + R[nb][2] * va.z + R[nb][3] * va.w
                      + R[nb][4] * vb.x + R[nb][5] * vb.y + R[nb][6] * vb.z + R[nb][7] * vb.w
                      + R[nb][8] * vc.x + R[nb][9] * vc.y + R[nb][10] * vc.z + R[nb][11] * vc.w
                      + R[nb][12] * vd.x + R[nb][13] * vd.y + R[nb][14] * vd.z + R[nb][15] * vd.w;
            }
            #pragma unroll
            for (int nb = 0; nb < 4; ++nb) {
                d[nb] += __shfl_xor(d[nb], 1);
                d[nb] += __shfl_xor(d[nb], 2);
                d[nb] += __shfl_xor(d[nb], 4);
            }
            float t01 = (s & 1) ? d[1] : d[0];
            float t23 = (s & 1) ? d[3] : d[2];
            float Dv = (s & 2) ? t23 : t01;

            int sbit = (ow >> tt) & 1;
            bool valid = (n0 < HALF_N) && (n1 < HALF_N);
            float ad = fabsf(Dv);
            float contr = -fmaxf(sbit ? Dv : -Dv, 0.f)
                          - 0.5f * __logf(1.f + __expf(-2.f * ad));
            sum += valid ? contr : 0.f;
            n1 += sbit; n0 += 1 - sbit;

            float4 ra = *(const float4*)&rbuf[base];
            float4 rb = *(const float4*)&rbuf[base + 4];
            float4 rc = *(const float4*)&rbuf[base + 8];
            float4 rd = *(const float4*)&rbuf[base + 12];
            #pragma unroll
            for (int nb = 0; nb < 4; ++nb) {
                if ((wh[nb] >> tt) & 1) {
                    R[nb][0] *= ra.x;  R[nb][1] *= ra.y;  R[nb][2] *= ra.z;  R[nb][3] *= ra.w;
                    R[nb][4] *= rb.x;  R[nb][5] *= rb.y;  R[nb][6] *= rb.z;  R[nb][7] *= rb.w;
                    R[nb][8] *= rc.x;  R[nb][9] *= rc.y;  R[nb][10] *= rc.z; R[nb][11] *= rc.w;
                    R[nb][12] *= rd.x; R[nb][13] *= rd.y; R[nb][14] *= rd.z; R[nb][15] *= rd.w;
                }
            }
        }
    }
    if (s < 4) atomicAdd(&out[b_own], sum);
}

extern "C" void kernel_launch(void* const* d_in, const int* in_sizes, int n_in,
                              void* d_out, int out_size, void* d_ws, size_t ws_size,
                              hipStream_t stream) {
    const int*   inputs  = (const int*)d_in[0];     // (B, L) int32
    const float* epsilon = (const float*)d_in[1];   // (D, M, L) f32
    float* out = (float*)d_out;                     // (B,) f32

    char* ws = (char*)d_ws;
    float* w_tab  = (float*)(ws + OFF_W);
    float* r_tab  = (float*)(ws + OFF_R);
    u64*   bits   = (u64*)  (ws + OFF_BITS);
    float* pp     = (float*)(ws + OFF_PP);
    unsigned short* lrT = (unsigned short*)(ws + OFF_LR);
    unsigned short* Rq  = (unsigned short*)(ws + OFF_RQ);

    k_pack<<<(B_N * L_N) / 256, 256, 0, stream>>>(inputs, bits);
    k_eps_pp<<<L_N / 64, M_N, 0, stream>>>(epsilon, pp);
    k_eps_wr<<<L_N / 64, M_N, 0, stream>>>(epsilon, pp, w_tab, r_tab, lrT);
    hipMemsetAsync(d_out, 0, B_N * sizeof(float), stream);
    k_slog<<<B_N / 32, 256, 0, stream>>>(bits, lrT, Rq);
    k_main<<<(B_N / 128) * C_N, 256, 0, stream>>>(bits, w_tab, r_tab, Rq, out);
}

// Round 5
// 202.280 us; speedup vs baseline: 3.3781x; 1.0630x over previous
//
#include <hip/hip_runtime.h>

typedef unsigned long long u64;
typedef unsigned int uint32;
typedef short short8 __attribute__((ext_vector_type(8)));
typedef float f32x4 __attribute__((ext_vector_type(4)));

#define B_N 8192
#define L_N 1024
#define M_N 128
#define C_N 16         // chunks over L
#define CH_N 64        // steps per chunk
#define HALF_N 512
#define SL 20          // padded 16-float slice stride
#define ROWF (8 * SL)  // 160 floats per staged step row

// ws layout (bytes)
#define OFF_W    0            // w[i][m]  f32: 512KB
#define OFF_R    0x80000      // r[i][m]  f32: 512KB
#define OFF_BITS 0x100000     // bits[b][16] u64: 1MB
#define OFF_LR   0x208000     // lrT[m][t] bf16: 128*1024*2 = 256KB
#define OFF_RQ   0x248000     // Rq[c][b][m] bf16: 16*8192*128*2 = 32MB

__device__ __forceinline__ unsigned short f32_bf16(float f) {
    union { float f; unsigned u; } x; x.f = f;
    unsigned u = x.u + 0x7FFFu + ((x.u >> 16) & 1u);   // RNE
    return (unsigned short)(u >> 16);
}
__device__ __forceinline__ float bf16lo(uint32 w) {
    union { unsigned u; float f; } x; x.u = w << 16; return x.f;
}
__device__ __forceinline__ float bf16hi(uint32 w) {
    union { unsigned u; float f; } x; x.u = w & 0xFFFF0000u; return x.f;
}

// ---------------- K0: pack spins to bits (inputs are 0/1) ----------------
__global__ __launch_bounds__(256) void k_pack(const int* __restrict__ inp, u64* __restrict__ bits) {
    int g = blockIdx.x * 256 + threadIdx.x;
    int v = inp[g];
    u64 m = __ballot(v != 0);
    if ((threadIdx.x & 63) == 0) bits[g >> 6] = m;   // word = b*16 + c
}

// ---- K1: merged eps tables. 128 blocks (one m) x 64 lanes (16 steps) ----
// w[i][m]=E0_i*(e0-e1), r[i][m]=e1/e0, lrT[m][i]=bf16(log2 r)
__global__ __launch_bounds__(64) void k_eps(const float* __restrict__ eps,
        float* __restrict__ w, float* __restrict__ r, unsigned short* __restrict__ lrT) {
    int m = blockIdx.x, lane = threadIdx.x;
    const float* e0 = eps + (size_t)m * L_N + lane * 16;
    const float* e1 = eps + (size_t)(M_N + m) * L_N + lane * 16;
    float a[16], b[16];
    #pragma unroll
    for (int j = 0; j < 16; j += 4) {
        *(float4*)&a[j] = *(const float4*)&e0[j];
        *(float4*)&b[j] = *(const float4*)&e1[j];
    }
    float local = 1.f;
    #pragma unroll
    for (int j = 0; j < 16; ++j) local *= a[j];
    // inclusive scan -> exclusive
    float sc = local;
    #pragma unroll
    for (int d = 1; d < 64; d <<= 1) {
        float up = __shfl_up(sc, d);
        if (lane >= d) sc *= up;
    }
    float prev = __shfl_up(sc, 1);
    float E = (lane == 0) ? 1.f : prev;
    int i0 = lane * 16;
    #pragma unroll
    for (int j = 0; j < 16; ++j) {
        float rat = b[j] / a[j];
        w[(size_t)(i0 + j) * M_N + m] = E * (a[j] - b[j]);
        r[(size_t)(i0 + j) * M_N + m] = rat;
        lrT[(size_t)m * L_N + i0 + j] = f32_bf16(__log2f(rat));
        E *= a[j];
    }
}

// ---- K2: per-chunk MFMA log-sums -> Rq (bf16, raw Slog), fully parallel -
// block = (c, 2 btiles); wave = (btile, m-half). No chunk loop.
__global__ __launch_bounds__(256) void k_slogsum(const u64* __restrict__ bits,
        const unsigned short* __restrict__ lrT, unsigned short* __restrict__ Rq) {
    int c = blockIdx.x & (C_N - 1);
    int bt2 = blockIdx.x >> 4;
    int wid = threadIdx.x >> 6, lane = threadIdx.x & 63;
    int btile = bt2 * 2 + (wid >> 1);
    int mbase = (wid & 1) * 64;
    int col = lane & 15, quad = lane >> 4;
    int b_row = btile * 16 + col;

    u64 wv = bits[(size_t)b_row * 16 + c];
    short8 a0, a1;
    #pragma unroll
    for (int j = 0; j < 8; ++j) {
        a0[j] = (short)((((wv >> (quad * 8 + j)) & 1) != 0) ? 0x3F80 : 0);
        a1[j] = (short)((((wv >> (32 + quad * 8 + j)) & 1) != 0) ? 0x3F80 : 0);
    }
    #pragma unroll
    for (int mt = 0; mt < 4; ++mt) {
        int m = mbase + mt * 16 + col;
        const unsigned short* bp = lrT + (size_t)m * L_N + c * 64 + quad * 8;
        union { uint4 u; short8 s; } bf0, bf1;
        bf0.u = *(const uint4*)bp;
        bf1.u = *(const uint4*)(bp + 32);
        f32x4 acc = (f32x4){0.f, 0.f, 0.f, 0.f};
        acc = __builtin_amdgcn_mfma_f32_16x16x32_bf16(a0, bf0.s, acc, 0, 0, 0);
        acc = __builtin_amdgcn_mfma_f32_16x16x32_bf16(a1, bf1.s, acc, 0, 0, 0);
        #pragma unroll
        for (int reg = 0; reg < 4; ++reg) {
            int b = btile * 16 + quad * 4 + reg;
            Rq[((size_t)c * B_N + b) * M_N + mbase + mt * 16 + col] = f32_bf16(acc[reg]);
        }
    }
}

// ---- K2b: in-place f32 cumsum of chunk log-sums + exp2 -> excl prefix ---
__global__ __launch_bounds__(256) void k_prefix(unsigned short* __restrict__ Rq) {
    int t = blockIdx.x * 256 + threadIdx.x;    // t in [0, B*M)
    int b = t >> 7, m = t & 127;
    float p = 0.f;
    for (int c = 0; c < C_N; ++c) {
        size_t idx = ((size_t)c * B_N + b) * M_N + m;
        union { unsigned u; float f; } x; x.u = ((unsigned)Rq[idx]) << 16;
        Rq[idx] = f32_bf16(exp2f(p));
        p += x.f;
    }
}

// ---------------- K3: main loop (8-lane groups, NB=4, half-chunk LDS) ----
__global__ __launch_bounds__(256, 4) void k_main(const u64* __restrict__ bits,
        const float* __restrict__ w, const float* __restrict__ r,
        const unsigned short* __restrict__ Rq, float* __restrict__ out) {
    __shared__ float wbuf[32 * ROWF];   // 20KB
    __shared__ float rbuf[32 * ROWF];   // 20KB
    int c = blockIdx.x & (C_N - 1);
    int bblk = blockIdx.x >> 4;
    int lane = threadIdx.x & 63, wid = threadIdx.x >> 6;
    int s = lane & 7, g = lane >> 3;
    int b0 = bblk * 128 + wid * 32 + g * 4;
    int b_own = b0 + (s & 3);

    // prefix load: R[nb][k], m = s*16 + k
    float R[4][16];
    #pragma unroll
    for (int nb = 0; nb < 4; ++nb) {
        const uint4* src = (const uint4*)(Rq + ((size_t)c * B_N + (b0 + nb)) * M_N + s * 16);
        #pragma unroll
        for (int u_ = 0; u_ < 2; ++u_) {
            uint4 pv = src[u_];
            R[nb][u_ * 8 + 0] = bf16lo(pv.x); R[nb][u_ * 8 + 1] = bf16hi(pv.x);
            R[nb][u_ * 8 + 2] = bf16lo(pv.y); R[nb][u_ * 8 + 3] = bf16hi(pv.y);
            R[nb][u_ * 8 + 4] = bf16lo(pv.z); R[nb][u_ * 8 + 5] = bf16hi(pv.z);
            R[nb][u_ * 8 + 6] = bf16lo(pv.w); R[nb][u_ * 8 + 7] = bf16hi(pv.w);
        }
    }
    int n1 = 0;
    for (int k = 0; k < c; ++k) n1 += __popcll(bits[(size_t)b_own * 16 + k]);
    int n0 = c * CH_N - n1;

    float sum = 0.f;
    for (int h = 0; h < 2; ++h) {
        __syncthreads();
        const float4* srcw = (const float4*)(w + ((size_t)c * CH_N + h * 32) * M_N);
        const float4* srcr = (const float4*)(r + ((size_t)c * CH_N + h * 32) * M_N);
        for (int t = threadIdx.x; t < 32 * 32; t += 256) {
            int i = t >> 5, mq = t & 31;
            int dst = i * ROWF + (mq >> 2) * SL + (mq & 3) * 4;
            *(float4*)&wbuf[dst] = srcw[t];
            *(float4*)&rbuf[dst] = srcr[t];
        }
        __syncthreads();

        uint32 wh[4];
        #pragma unroll
        for (int nb = 0; nb < 4; ++nb)
            wh[nb] = (uint32)(bits[(size_t)(b0 + nb) * 16 + c] >> (h * 32));
        uint32 owa = (s & 1) ? wh[1] : wh[0];
        uint32 owb = (s & 1) ? wh[3] : wh[2];
        uint32 ow = (s & 2) ? owb : owa;

        for (int tt = 0; tt < 32; ++tt) {
            int base = tt * ROWF + s * SL;
            float4 va = *(const float4*)&wbuf[base];
            float4 vb = *(const float4*)&wbuf[base + 4];
            float4 vc = *(const float4*)&wbuf[base + 8];
            float4 vd = *(const float4*)&wbuf[base + 12];
            float d[4];
            #pragma unroll
            for (int nb = 0; nb < 4; ++nb) {
                d[nb] = R[nb][0] * va.x + R[nb][1] * va.y + R[nb][2] * va.z + R[nb][3] * va.w
                      + R[nb][4] * vb.x + R[nb][5] * vb.y + R[nb][6] * vb.z + R[nb][7] * vb.w
                      + R[nb][8] * vc.x + R[nb][9] * vc.y + R[nb][10] * vc.z + R[nb][11] * vc.w
                      + R[nb][12] * vd.x + R[nb][13] * vd.y + R[nb][14] * vd.z + R[nb][15] * vd.w;
            }
            #pragma unroll
            for (int nb = 0; nb < 4; ++nb) {
                d[nb] += __shfl_xor(d[nb], 1);
                d[nb] += __shfl_xor(d[nb], 2);
                d[nb] += __shfl_xor(d[nb], 4);
            }
            float t01 = (s & 1) ? d[1] : d[0];
            float t23 = (s & 1) ? d[3] : d[2];
            float Dv = (s & 2) ? t23 : t01;

            int sbit = (ow >> tt) & 1;
            bool valid = (n0 < HALF_N) && (n1 < HALF_N);
            float ad = fabsf(Dv);
            float contr = -fmaxf(sbit ? Dv : -Dv, 0.f)
                          - 0.5f * __logf(1.f + __expf(-2.f * ad));
            sum += valid ? contr : 0.f;
            n1 += sbit; n0 += 1 - sbit;

            float4 ra = *(const float4*)&rbuf[base];
            float4 rb = *(const float4*)&rbuf[base + 4];
            float4 rc = *(const float4*)&rbuf[base + 8];
            float4 rd = *(const float4*)&rbuf[base + 12];
            #pragma unroll
            for (int nb = 0; nb < 4; ++nb) {
                if ((wh[nb] >> tt) & 1) {
                    R[nb][0] *= ra.x;  R[nb][1] *= ra.y;  R[nb][2] *= ra.z;  R[nb][3] *= ra.w;
                    R[nb][4] *= rb.x;  R[nb][5] *= rb.y;  R[nb][6] *= rb.z;  R[nb][7] *= rb.w;
                    R[nb][8] *= rc.x;  R[nb][9] *= rc.y;  R[nb][10] *= rc.z; R[nb][11] *= rc.w;
                    R[nb][12] *= rd.x; R[nb][13] *= rd.y; R[nb][14] *= rd.z; R[nb][15] *= rd.w;
                }
            }
        }
    }
    if (s < 4) atomicAdd(&out[b_own], sum);
}

extern "C" void kernel_launch(void* const* d_in, const int* in_sizes, int n_in,
                              void* d_out, int out_size, void* d_ws, size_t ws_size,
                              hipStream_t stream) {
    const int*   inputs  = (const int*)d_in[0];     // (B, L) int32
    const float* epsilon = (const float*)d_in[1];   // (D, M, L) f32
    float* out = (float*)d_out;                     // (B,) f32

    char* ws = (char*)d_ws;
    float* w_tab  = (float*)(ws + OFF_W);
    float* r_tab  = (float*)(ws + OFF_R);
    u64*   bits   = (u64*)  (ws + OFF_BITS);
    unsigned short* lrT = (unsigned short*)(ws + OFF_LR);
    unsigned short* Rq  = (unsigned short*)(ws + OFF_RQ);

    k_pack<<<(B_N * L_N) / 256, 256, 0, stream>>>(inputs, bits);
    k_eps<<<M_N, 64, 0, stream>>>(epsilon, w_tab, r_tab, lrT);
    hipMemsetAsync(d_out, 0, B_N * sizeof(float), stream);
    k_slogsum<<<(B_N / 32) * C_N, 256, 0, stream>>>(bits, lrT, Rq);
    k_prefix<<<(B_N * M_N) / 256, 256, 0, stream>>>(Rq);
    k_main<<<(B_N / 128) * C_N, 256, 0, stream>>>(bits, w_tab, r_tab, Rq, out);
}

// Round 6
// 199.112 us; speedup vs baseline: 3.4318x; 1.0159x over previous
//
#include <hip/hip_runtime.h>

typedef unsigned long long u64;
typedef unsigned int uint32;
typedef short short8 __attribute__((ext_vector_type(8)));
typedef float f32x4 __attribute__((ext_vector_type(4)));

#define B_N 8192
#define L_N 1024
#define M_N 128
#define C_N 16         // chunks over L
#define CH_N 64        // steps per chunk
#define HALF_N 512
#define SL 20          // padded 16-float slice stride (even -> float4-aligned)
#define ROWF (8 * SL)  // 160 floats per staged step row

// ws layout (bytes)
#define OFF_W    0            // w[i][m]  f32: 512KB
#define OFF_R    0x80000      // r[i][m]  f32: 512KB
#define OFF_BITS 0x100000     // bits[b][16] u64: 1MB
#define OFF_LR   0x208000     // lrT[m][t] bf16: 128*1024*2 = 256KB
#define OFF_RQ   0x248000     // Rq[c][b][m] bf16: 16*8192*128*2 = 32MB

__device__ __forceinline__ unsigned short f32_bf16(float f) {
    union { float f; unsigned u; } x; x.f = f;
    unsigned u = x.u + 0x7FFFu + ((x.u >> 16) & 1u);   // RNE
    return (unsigned short)(u >> 16);
}
__device__ __forceinline__ float bf16lo(uint32 w) {
    union { unsigned u; float f; } x; x.u = w << 16; return x.f;
}
__device__ __forceinline__ float bf16hi(uint32 w) {
    union { unsigned u; float f; } x; x.u = w & 0xFFFF0000u; return x.f;
}

// CDNA packed fp32: 2 floats/lane/instruction (VGPR-pair operands)
__device__ __forceinline__ float2 pk_fma(float2 a, float2 b, float2 c) {
    float2 d;
    asm("v_pk_fma_f32 %0, %1, %2, %3" : "=v"(d) : "v"(a), "v"(b), "v"(c));
    return d;
}
__device__ __forceinline__ float2 pk_mul(float2 a, float2 b) {
    float2 d;
    asm("v_pk_mul_f32 %0, %1, %2" : "=v"(d) : "v"(a), "v"(b));
    return d;
}

// ---------------- K0: pack spins to bits (inputs are 0/1) ----------------
__global__ __launch_bounds__(256) void k_pack(const int* __restrict__ inp, u64* __restrict__ bits) {
    int g = blockIdx.x * 256 + threadIdx.x;
    int v = inp[g];
    u64 m = __ballot(v != 0);
    if ((threadIdx.x & 63) == 0) bits[g >> 6] = m;   // word = b*16 + c
}

// ---- K1: merged eps tables. 128 blocks (one m) x 64 lanes (16 steps) ----
__global__ __launch_bounds__(64) void k_eps(const float* __restrict__ eps,
        float* __restrict__ w, float* __restrict__ r, unsigned short* __restrict__ lrT) {
    int m = blockIdx.x, lane = threadIdx.x;
    const float* e0 = eps + (size_t)m * L_N + lane * 16;
    const float* e1 = eps + (size_t)(M_N + m) * L_N + lane * 16;
    float a[16], b[16];
    #pragma unroll
    for (int j = 0; j < 16; j += 4) {
        *(float4*)&a[j] = *(const float4*)&e0[j];
        *(float4*)&b[j] = *(const float4*)&e1[j];
    }
    float local = 1.f;
    #pragma unroll
    for (int j = 0; j < 16; ++j) local *= a[j];
    float sc = local;
    #pragma unroll
    for (int d = 1; d < 64; d <<= 1) {
        float up = __shfl_up(sc, d);
        if (lane >= d) sc *= up;
    }
    float prev = __shfl_up(sc, 1);
    float E = (lane == 0) ? 1.f : prev;
    int i0 = lane * 16;
    #pragma unroll
    for (int j = 0; j < 16; ++j) {
        float rat = b[j] / a[j];
        w[(size_t)(i0 + j) * M_N + m] = E * (a[j] - b[j]);
        r[(size_t)(i0 + j) * M_N + m] = rat;
        lrT[(size_t)m * L_N + i0 + j] = f32_bf16(__log2f(rat));
        E *= a[j];
    }
}

// ---- K2: fused MFMA chunk log-sums + f32 cumsum + exp2 -> excl prefix ---
// 512 blocks (btile) x 4 waves (m-quarter). Chunk-serial, cumsum in regs.
__global__ __launch_bounds__(256) void k_slog2(const u64* __restrict__ bits,
        const unsigned short* __restrict__ lrT, unsigned short* __restrict__ Rq) {
    int btile = blockIdx.x;
    int mq = threadIdx.x >> 6, lane = threadIdx.x & 63;
    int col = lane & 15, quad = lane >> 4;
    int b_row = btile * 16 + col;
    const u64* brow = bits + (size_t)b_row * 16;

    f32x4 cum[2];
    cum[0] = (f32x4){0.f, 0.f, 0.f, 0.f};
    cum[1] = (f32x4){0.f, 0.f, 0.f, 0.f};

    for (int c = 0; c < C_N; ++c) {
        // exclusive prefix: write exp2(cum) BEFORE accumulating chunk c
        #pragma unroll
        for (int mt = 0; mt < 2; ++mt) {
            #pragma unroll
            for (int reg = 0; reg < 4; ++reg) {
                int b = btile * 16 + quad * 4 + reg;
                int m = mq * 32 + mt * 16 + col;
                Rq[((size_t)c * B_N + b) * M_N + m] = f32_bf16(exp2f(cum[mt][reg]));
            }
        }
        u64 wv = brow[c];
        short8 a0, a1;
        #pragma unroll
        for (int j = 0; j < 8; ++j) {
            a0[j] = (short)((((wv >> (quad * 8 + j)) & 1) != 0) ? 0x3F80 : 0);
            a1[j] = (short)((((wv >> (32 + quad * 8 + j)) & 1) != 0) ? 0x3F80 : 0);
        }
        #pragma unroll
        for (int mt = 0; mt < 2; ++mt) {
            int m = mq * 32 + mt * 16 + col;
            const unsigned short* bp = lrT + (size_t)m * L_N + c * 64 + quad * 8;
            union { uint4 u; short8 s; } bf0, bf1;
            bf0.u = *(const uint4*)bp;
            bf1.u = *(const uint4*)(bp + 32);
            cum[mt] = __builtin_amdgcn_mfma_f32_16x16x32_bf16(a0, bf0.s, cum[mt], 0, 0, 0);
            cum[mt] = __builtin_amdgcn_mfma_f32_16x16x32_bf16(a1, bf1.s, cum[mt], 0, 0, 0);
        }
    }
}

// ---------------- K3: main loop (packed-f32, 8-lane groups, NB=4) --------
__global__ __launch_bounds__(256, 4) void k_main(const u64* __restrict__ bits,
        const float* __restrict__ w, const float* __restrict__ r,
        const unsigned short* __restrict__ Rq, float* __restrict__ out) {
    __shared__ float wbuf[32 * ROWF];   // 20KB
    __shared__ float rbuf[32 * ROWF];   // 20KB
    int c = blockIdx.x & (C_N - 1);
    int bblk = blockIdx.x >> 4;
    int lane = threadIdx.x & 63, wid = threadIdx.x >> 6;
    int s = lane & 7, g = lane >> 3;
    int b0 = bblk * 128 + wid * 32 + g * 4;
    int b_own = b0 + (s & 3);

    // prefix load: R2[nb][j] pairs, m = s*16 + 2j
    float2 R2[4][8];
    #pragma unroll
    for (int nb = 0; nb < 4; ++nb) {
        const uint4* src = (const uint4*)(Rq + ((size_t)c * B_N + (b0 + nb)) * M_N + s * 16);
        #pragma unroll
        for (int u_ = 0; u_ < 2; ++u_) {
            uint4 pv = src[u_];
            R2[nb][u_ * 4 + 0] = make_float2(bf16lo(pv.x), bf16hi(pv.x));
            R2[nb][u_ * 4 + 1] = make_float2(bf16lo(pv.y), bf16hi(pv.y));
            R2[nb][u_ * 4 + 2] = make_float2(bf16lo(pv.z), bf16hi(pv.z));
            R2[nb][u_ * 4 + 3] = make_float2(bf16lo(pv.w), bf16hi(pv.w));
        }
    }
    int n1 = 0;
    for (int k = 0; k < c; ++k) n1 += __popcll(bits[(size_t)b_own * 16 + k]);
    int n0 = c * CH_N - n1;

    float sum = 0.f;
    for (int h = 0; h < 2; ++h) {
        __syncthreads();
        const float4* srcw = (const float4*)(w + ((size_t)c * CH_N + h * 32) * M_N);
        const float4* srcr = (const float4*)(r + ((size_t)c * CH_N + h * 32) * M_N);
        for (int t = threadIdx.x; t < 32 * 32; t += 256) {
            int i = t >> 5, mqd = t & 31;
            int dst = i * ROWF + (mqd >> 2) * SL + (mqd & 3) * 4;
            *(float4*)&wbuf[dst] = srcw[t];
            *(float4*)&rbuf[dst] = srcr[t];
        }
        __syncthreads();

        uint32 wh[4];
        #pragma unroll
        for (int nb = 0; nb < 4; ++nb)
            wh[nb] = (uint32)(bits[(size_t)(b0 + nb) * 16 + c] >> (h * 32));
        uint32 owa = (s & 1) ? wh[1] : wh[0];
        uint32 owb = (s & 1) ? wh[3] : wh[2];
        uint32 ow = (s & 2) ? owb : owa;

        for (int tt = 0; tt < 32; ++tt) {
            int base = tt * ROWF + s * SL;
            const float2* wp = (const float2*)&wbuf[base];
            float2 w2[8];
            #pragma unroll
            for (int j = 0; j < 8; ++j) w2[j] = wp[j];

            float d[4];
            #pragma unroll
            for (int nb = 0; nb < 4; ++nb) {
                float2 acc = pk_mul(R2[nb][0], w2[0]);
                #pragma unroll
                for (int j = 1; j < 8; ++j) acc = pk_fma(R2[nb][j], w2[j], acc);
                d[nb] = acc.x + acc.y;
            }
            #pragma unroll
            for (int nb = 0; nb < 4; ++nb) {
                d[nb] += __shfl_xor(d[nb], 1);
                d[nb] += __shfl_xor(d[nb], 2);
            }
            int sb3 = s & 3;
            float sel = d[0];
            if (sb3 == 1) sel = d[1];
            if (sb3 == 2) sel = d[2];
            if (sb3 == 3) sel = d[3];
            sel += __shfl_xor(sel, 4);
            float Dv = sel;

            int sbit = (ow >> tt) & 1;
            bool valid = (n0 < HALF_N) && (n1 < HALF_N);
            float ad = fabsf(Dv);
            float contr = -fmaxf(sbit ? Dv : -Dv, 0.f)
                          - 0.5f * __logf(1.f + __expf(-2.f * ad));
            sum += valid ? contr : 0.f;
            n1 += sbit; n0 += 1 - sbit;

            const float2* rp = (const float2*)&rbuf[base];
            float2 r2[8];
            #pragma unroll
            for (int j = 0; j < 8; ++j) r2[j] = rp[j];
            #pragma unroll
            for (int nb = 0; nb < 4; ++nb) {
                if ((wh[nb] >> tt) & 1) {
                    #pragma unroll
                    for (int j = 0; j < 8; ++j) R2[nb][j] = pk_mul(R2[nb][j], r2[j]);
                }
            }
        }
    }
    if (s < 4) atomicAdd(&out[b_own], sum);
}

extern "C" void kernel_launch(void* const* d_in, const int* in_sizes, int n_in,
                              void* d_out, int out_size, void* d_ws, size_t ws_size,
                              hipStream_t stream) {
    const int*   inputs  = (const int*)d_in[0];     // (B, L) int32
    const float* epsilon = (const float*)d_in[1];   // (D, M, L) f32
    float* out = (float*)d_out;                     // (B,) f32

    char* ws = (char*)d_ws;
    float* w_tab  = (float*)(ws + OFF_W);
    float* r_tab  = (float*)(ws + OFF_R);
    u64*   bits   = (u64*)  (ws + OFF_BITS);
    unsigned short* lrT = (unsigned short*)(ws + OFF_LR);
    unsigned short* Rq  = (unsigned short*)(ws + OFF_RQ);

    k_pack<<<(B_N * L_N) / 256, 256, 0, stream>>>(inputs, bits);
    k_eps<<<M_N, 64, 0, stream>>>(epsilon, w_tab, r_tab, lrT);
    hipMemsetAsync(d_out, 0, B_N * sizeof(float), stream);
    k_slog2<<<B_N / 16, 256, 0, stream>>>(bits, lrT, Rq);
    k_main<<<(B_N / 128) * C_N, 256, 0, stream>>>(bits, w_tab, r_tab, Rq, out);
}

// Round 7
// 196.849 us; speedup vs baseline: 3.4713x; 1.0115x over previous
//
#include <hip/hip_runtime.h>

typedef unsigned long long u64;
typedef unsigned int uint32;
typedef short short8 __attribute__((ext_vector_type(8)));
typedef float f32x4 __attribute__((ext_vector_type(4)));
typedef float f32x2 __attribute__((ext_vector_type(2)));

#define B_N 8192
#define L_N 1024
#define M_N 128
#define C_N 16         // chunks over L
#define CH_N 64        // steps per chunk
#define HALF_N 512
#define SL 20          // padded 16-float slice stride (even -> float4-aligned)
#define ROWF (8 * SL)  // 160 floats per staged step row

// ws layout (bytes)
#define OFF_W    0            // w[i][m]  f32: 512KB
#define OFF_R    0x80000      // r[i][m]  f32: 512KB
#define OFF_BITS 0x100000     // bits[b][16] u64: 1MB
#define OFF_LR   0x208000     // lrT[m][t] bf16: 128*1024*2 = 256KB
#define OFF_RQ   0x248000     // Rq[c][b][m] bf16: 16*8192*128*2 = 32MB

__device__ __forceinline__ unsigned short f32_bf16(float f) {
    union { float f; unsigned u; } x; x.f = f;
    unsigned u = x.u + 0x7FFFu + ((x.u >> 16) & 1u);   // RNE
    return (unsigned short)(u >> 16);
}
__device__ __forceinline__ float bf16lo(uint32 w) {
    union { unsigned u; float f; } x; x.u = w << 16; return x.f;
}
__device__ __forceinline__ float bf16hi(uint32 w) {
    union { unsigned u; float f; } x; x.u = w & 0xFFFF0000u; return x.f;
}

// ---------------- K0: pack spins to bits (inputs are 0/1) ----------------
__global__ __launch_bounds__(256) void k_pack(const int* __restrict__ inp, u64* __restrict__ bits) {
    int g = blockIdx.x * 256 + threadIdx.x;
    int v = inp[g];
    u64 m = __ballot(v != 0);
    if ((threadIdx.x & 63) == 0) bits[g >> 6] = m;   // word = b*16 + c
}

// ---- K1: merged eps tables. 128 blocks (one m) x 64 lanes (16 steps) ----
__global__ __launch_bounds__(64) void k_eps(const float* __restrict__ eps,
        float* __restrict__ w, float* __restrict__ r, unsigned short* __restrict__ lrT) {
    int m = blockIdx.x, lane = threadIdx.x;
    const float* e0 = eps + (size_t)m * L_N + lane * 16;
    const float* e1 = eps + (size_t)(M_N + m) * L_N + lane * 16;
    float a[16], b[16];
    #pragma unroll
    for (int j = 0; j < 16; j += 4) {
        *(float4*)&a[j] = *(const float4*)&e0[j];
        *(float4*)&b[j] = *(const float4*)&e1[j];
    }
    float local = 1.f;
    #pragma unroll
    for (int j = 0; j < 16; ++j) local *= a[j];
    float sc = local;
    #pragma unroll
    for (int d = 1; d < 64; d <<= 1) {
        float up = __shfl_up(sc, d);
        if (lane >= d) sc *= up;
    }
    float prev = __shfl_up(sc, 1);
    float E = (lane == 0) ? 1.f : prev;
    int i0 = lane * 16;
    #pragma unroll
    for (int j = 0; j < 16; ++j) {
        float rat = b[j] / a[j];
        w[(size_t)(i0 + j) * M_N + m] = E * (a[j] - b[j]);
        r[(size_t)(i0 + j) * M_N + m] = rat;
        lrT[(size_t)m * L_N + i0 + j] = f32_bf16(__log2f(rat));
        E *= a[j];
    }
}

// ---- K2: fused MFMA chunk log-sums + f32 cumsum + exp2 -> excl prefix ---
// 1024 blocks = (btile, m-half); wave = one 16-m tile. Chunk-serial cumsum.
__global__ __launch_bounds__(256) void k_slog2(const u64* __restrict__ bits,
        const unsigned short* __restrict__ lrT, unsigned short* __restrict__ Rq) {
    int btile = blockIdx.x >> 1;
    int half = blockIdx.x & 1;
    int wid = threadIdx.x >> 6, lane = threadIdx.x & 63;
    int col = lane & 15, quad = lane >> 4;
    int m = (half * 4 + wid) * 16 + col;
    int b_row = btile * 16 + col;
    const u64* brow = bits + (size_t)b_row * 16;
    const unsigned short* lrow = lrT + (size_t)m * L_N;

    f32x4 cum = (f32x4){0.f, 0.f, 0.f, 0.f};

    for (int c = 0; c < C_N; ++c) {
        // exclusive prefix: write exp2(cum) BEFORE accumulating chunk c
        #pragma unroll
        for (int reg = 0; reg < 4; ++reg) {
            int b = btile * 16 + quad * 4 + reg;
            Rq[((size_t)c * B_N + b) * M_N + m] = f32_bf16(exp2f(cum[reg]));
        }
        u64 wv = brow[c];
        short8 a0, a1;
        #pragma unroll
        for (int j = 0; j < 8; ++j) {
            a0[j] = (short)((((wv >> (quad * 8 + j)) & 1) != 0) ? 0x3F80 : 0);
            a1[j] = (short)((((wv >> (32 + quad * 8 + j)) & 1) != 0) ? 0x3F80 : 0);
        }
        const unsigned short* bp = lrow + c * 64 + quad * 8;
        union { uint4 u; short8 s; } bf0, bf1;
        bf0.u = *(const uint4*)bp;
        bf1.u = *(const uint4*)(bp + 32);
        cum = __builtin_amdgcn_mfma_f32_16x16x32_bf16(a0, bf0.s, cum, 0, 0, 0);
        cum = __builtin_amdgcn_mfma_f32_16x16x32_bf16(a1, bf1.s, cum, 0, 0, 0);
    }
}

// ---------------- K3: main loop (v2f32 packed, 8-lane groups, NB=4) ------
__global__ __launch_bounds__(256, 4) void k_main(const u64* __restrict__ bits,
        const float* __restrict__ w, const float* __restrict__ r,
        const unsigned short* __restrict__ Rq, float* __restrict__ out) {
    __shared__ float wbuf[32 * ROWF];   // 20KB
    __shared__ float rbuf[32 * ROWF];   // 20KB
    int c = blockIdx.x & (C_N - 1);
    int bblk = blockIdx.x >> 4;
    int lane = threadIdx.x & 63, wid = threadIdx.x >> 6;
    int s = lane & 7, g = lane >> 3;
    int b0 = bblk * 128 + wid * 32 + g * 4;
    int b_own = b0 + (s & 3);

    // prefix load: R2[nb][j] pairs, m = s*16 + 2j
    f32x2 R2[4][8];
    #pragma unroll
    for (int nb = 0; nb < 4; ++nb) {
        const uint4* src = (const uint4*)(Rq + ((size_t)c * B_N + (b0 + nb)) * M_N + s * 16);
        #pragma unroll
        for (int u_ = 0; u_ < 2; ++u_) {
            uint4 pv = src[u_];
            R2[nb][u_ * 4 + 0] = (f32x2){bf16lo(pv.x), bf16hi(pv.x)};
            R2[nb][u_ * 4 + 1] = (f32x2){bf16lo(pv.y), bf16hi(pv.y)};
            R2[nb][u_ * 4 + 2] = (f32x2){bf16lo(pv.z), bf16hi(pv.z)};
            R2[nb][u_ * 4 + 3] = (f32x2){bf16lo(pv.w), bf16hi(pv.w)};
        }
    }
    int n1 = 0;
    for (int k = 0; k < c; ++k) n1 += __popcll(bits[(size_t)b_own * 16 + k]);
    int n0 = c * CH_N - n1;

    float sum = 0.f;
    for (int h = 0; h < 2; ++h) {
        __syncthreads();
        const float4* srcw = (const float4*)(w + ((size_t)c * CH_N + h * 32) * M_N);
        const float4* srcr = (const float4*)(r + ((size_t)c * CH_N + h * 32) * M_N);
        for (int t = threadIdx.x; t < 32 * 32; t += 256) {
            int i = t >> 5, mqd = t & 31;
            int dst = i * ROWF + (mqd >> 2) * SL + (mqd & 3) * 4;
            *(float4*)&wbuf[dst] = srcw[t];
            *(float4*)&rbuf[dst] = srcr[t];
        }
        __syncthreads();

        uint32 wh[4];
        #pragma unroll
        for (int nb = 0; nb < 4; ++nb)
            wh[nb] = (uint32)(bits[(size_t)(b0 + nb) * 16 + c] >> (h * 32));
        uint32 owa = (s & 1) ? wh[1] : wh[0];
        uint32 owb = (s & 1) ? wh[3] : wh[2];
        uint32 ow = (s & 2) ? owb : owa;

        for (int tt = 0; tt < 32; ++tt) {
            int base = tt * ROWF + s * SL;
            const f32x2* wp = (const f32x2*)&wbuf[base];
            f32x2 w2[8];
            #pragma unroll
            for (int j = 0; j < 8; ++j) w2[j] = wp[j];

            float d[4];
            #pragma unroll
            for (int nb = 0; nb < 4; ++nb) {
                f32x2 acc = R2[nb][0] * w2[0];
                #pragma unroll
                for (int j = 1; j < 8; ++j) acc += R2[nb][j] * w2[j];
                d[nb] = acc[0] + acc[1];
            }
            #pragma unroll
            for (int nb = 0; nb < 4; ++nb) {
                d[nb] += __shfl_xor(d[nb], 1);
                d[nb] += __shfl_xor(d[nb], 2);
            }
            int sb3 = s & 3;
            float sel = d[0];
            if (sb3 == 1) sel = d[1];
            if (sb3 == 2) sel = d[2];
            if (sb3 == 3) sel = d[3];
            sel += __shfl_xor(sel, 4);
            float Dv = sel;

            int sbit = (ow >> tt) & 1;
            bool valid = (n0 < HALF_N) && (n1 < HALF_N);
            float ad = fabsf(Dv);
            float contr = -fmaxf(sbit ? Dv : -Dv, 0.f)
                          - 0.5f * __logf(1.f + __expf(-2.f * ad));
            sum += valid ? contr : 0.f;
            n1 += sbit; n0 += 1 - sbit;

            const f32x2* rp = (const f32x2*)&rbuf[base];
            f32x2 r2[8];
            #pragma unroll
            for (int j = 0; j < 8; ++j) r2[j] = rp[j];
            #pragma unroll
            for (int nb = 0; nb < 4; ++nb) {
                if ((wh[nb] >> tt) & 1) {
                    #pragma unroll
                    for (int j = 0; j < 8; ++j) R2[nb][j] *= r2[j];
                }
            }
        }
    }
    if (s < 4) atomicAdd(&out[b_own], sum);
}

extern "C" void kernel_launch(void* const* d_in, const int* in_sizes, int n_in,
                              void* d_out, int out_size, void* d_ws, size_t ws_size,
                              hipStream_t stream) {
    const int*   inputs  = (const int*)d_in[0];     // (B, L) int32
    const float* epsilon = (const float*)d_in[1];   // (D, M, L) f32
    float* out = (float*)d_out;                     // (B,) f32

    char* ws = (char*)d_ws;
    float* w_tab  = (float*)(ws + OFF_W);
    float* r_tab  = (float*)(ws + OFF_R);
    u64*   bits   = (u64*)  (ws + OFF_BITS);
    unsigned short* lrT = (unsigned short*)(ws + OFF_LR);
    unsigned short* Rq  = (unsigned short*)(ws + OFF_RQ);

    k_pack<<<(B_N * L_N) / 256, 256, 0, stream>>>(inputs, bits);
    k_eps<<<M_N, 64, 0, stream>>>(epsilon, w_tab, r_tab, lrT);
    hipMemsetAsync(d_out, 0, B_N * sizeof(float), stream);
    k_slog2<<<(B_N / 16) * 2, 256, 0, stream>>>(bits, lrT, Rq);
    k_main<<<(B_N / 128) * C_N, 256, 0, stream>>>(bits, w_tab, r_tab, Rq, out);
}